// Round 5
// baseline (764.303 us; speedup 1.0000x reference)
//
#include <hip/hip_runtime.h>
#include <stdint.h>

#define LDIM 1024
#define DDIM 256
#define FDIM 32
#define NSEG 64
#define BM 64
#define BK 64

typedef __attribute__((ext_vector_type(4))) float f32x4;
typedef __attribute__((ext_vector_type(8))) short short8;
typedef __attribute__((ext_vector_type(4))) unsigned int u32x4;

__device__ __forceinline__ unsigned int pk2bf(float a, float b) {
  union { float f; unsigned int u; } x, y; x.f = a; y.f = b;
  unsigned int ua = x.u + 0x7FFFu + ((x.u >> 16) & 1u);
  unsigned int ub = y.u + 0x7FFFu + ((y.u >> 16) & 1u);
  return (ua >> 16) | (ub & 0xFFFF0000u);
}

__device__ __forceinline__ unsigned short f2bf(float f) {
  union { float f; unsigned int u; } v; v.f = f;
  unsigned int r = v.u + 0x7FFFu + ((v.u >> 16) & 1u);
  return (unsigned short)(r >> 16);
}

// ---- prep: W1^T (bf16) rows 0..255, (W1@Wa1)^T rows 256..287 into ws ----
__global__ void prep_w1t(const float* __restrict__ W1, const float* __restrict__ Wa1,
                         unsigned short* __restrict__ w1t) {
  __shared__ float rowf[DDIM];
  const int k = blockIdx.x;
  const int t = threadIdx.x;
  float v = W1[(size_t)k * DDIM + t];
  rowf[t] = v;
  w1t[(size_t)t * LDIM + k] = f2bf(v);
  __syncthreads();
  if (t < FDIM) {
    float a = 0.f;
    for (int c = 0; c < DDIM; ++c) a += rowf[c] * Wa1[c * FDIM + t];
    w1t[(size_t)(DDIM + t) * LDIM + k] = f2bf(a);
  }
}

// ---- prep: zero accumulators, bz = b1@Wa1 + ba1 ----
__global__ void prep_misc(const float* __restrict__ b1, const float* __restrict__ Wa1,
                          const float* __restrict__ ba1, float* __restrict__ bz,
                          float* __restrict__ acc_eh, float* __restrict__ accE) {
  const int b = blockIdx.x, t = threadIdx.x;
  acc_eh[b * DDIM + t] = 0.f;
  if (t == 0) accE[b] = 0.f;
  if (b == 0 && t < FDIM) {
    float a = ba1[t];
    for (int c = 0; c < DDIM; ++c) a += b1[c] * Wa1[c * FDIM + t];
    bz[t] = a;
  }
}

// ---- main fused kernel: LDS-shared A (x read once) + raw barrier-1 +
//      depth-2 A prefetch + counted-vmcnt barrier-2 ----
__global__ __launch_bounds__(256, 3) void fused_main(
    const float* __restrict__ x, const int* __restrict__ idxs,
    const unsigned short* __restrict__ w1t, const float* __restrict__ bz,
    const float* __restrict__ Wa2, const float* __restrict__ ba2,
    float* __restrict__ acc_eh, float* __restrict__ accE)
{
  __shared__ __align__(16) unsigned short xlds[BM][72];      // 64 rows x 144B (2-way free)
  __shared__ __align__(16) unsigned char blds[288 * 128];    // 288 rows x 128B, XOR-swizzled
  __shared__ float logit_s[BM];
  __shared__ float e_s[BM];
  __shared__ int seg_s[BM];

  const int tid = threadIdx.x;
  const int lane = tid & 63;
  const int wid = tid >> 6;       // 0..3
  const int wr = wid >> 1;        // 0..1 : 32-row half
  const int wc = wid & 1;         // 0..1 : 144-col half
  const int g = lane >> 4;
  const int cl = lane & 15;
  const int row0 = blockIdx.x * BM;

  if (tid < BM) seg_s[tid] = idxs[row0 + tid];

  f32x4 acc[2][9];
  const f32x4 zero4 = {0.f, 0.f, 0.f, 0.f};
  #pragma unroll
  for (int m = 0; m < 2; ++m)
    #pragma unroll
    for (int n = 0; n < 9; ++n) acc[m][n] = zero4;

  const int arow = tid >> 2;
  const int aq = tid & 3;
  const char* w1tb = (const char*)w1t;
  const float* gxa = x + (size_t)(row0 + arow) * LDIM + aq * 16;

  // two named staging sets (depth-2 A pipeline; static names — rule #20)
  f32x4 e0, e1, e2, e3;   // even-kt set
  f32x4 o0, o1, o2, o3;   // odd-kt set
  e0 = *(const f32x4*)(gxa);      e1 = *(const f32x4*)(gxa + 4);
  e2 = *(const f32x4*)(gxa + 8);  e3 = *(const f32x4*)(gxa + 12);
  o0 = *(const f32x4*)(gxa + 64); o1 = *(const f32x4*)(gxa + 68);
  o2 = *(const f32x4*)(gxa + 72); o3 = *(const f32x4*)(gxa + 76);

  auto step = [&](int kt, f32x4& c0, f32x4& c1, f32x4& c2, f32x4& c3) {
    // barrier-1: RAW (no vmcnt drain) — prev MFMA consumed its ds_reads already;
    // A(kt)/A(kt+1) global loads stay in flight across it.
    __builtin_amdgcn_s_barrier();
    // stage B(kt): 9 x global_load_lds (async)
    #pragma unroll
    for (int j = 0; j < 9; ++j) {
      int byteoff = j * 4096 + tid * 16;
      int brow = byteoff >> 7;
      int bcolb = byteoff & 127;
      int srcb = brow * 2048 + kt * 128 + (bcolb ^ ((brow & 7) << 4));
      __builtin_amdgcn_global_load_lds(
          (const __attribute__((address_space(1))) unsigned int*)(w1tb + srcb),
          (__attribute__((address_space(3))) unsigned int*)(blds + j * 4096 + wid * 1024),
          16, 0, 0);
    }
    // pin issue order: all 9 B loads precede the A(kt+2) loads (vmcnt(4) below
    // relies on FIFO order — B must be strictly older than A(kt+2))
    __builtin_amdgcn_sched_barrier(0);
    // pack A(kt) -> bf16 -> xlds (compiler inserts precise vmcnt for A(kt) only)
    u32x4 q0, q1;
    q0[0] = pk2bf(c0[0], c0[1]); q0[1] = pk2bf(c0[2], c0[3]);
    q0[2] = pk2bf(c1[0], c1[1]); q0[3] = pk2bf(c1[2], c1[3]);
    q1[0] = pk2bf(c2[0], c2[1]); q1[1] = pk2bf(c2[2], c2[3]);
    q1[2] = pk2bf(c3[0], c3[1]); q1[3] = pk2bf(c3[2], c3[3]);
    *(u32x4*)&xlds[arow][aq * 16] = q0;
    *(u32x4*)&xlds[arow][aq * 16 + 8] = q1;
    if (kt < 14) {
      // issue A(kt+2) into the just-freed set — in flight for ~2 full steps
      const float* gp = gxa + (kt + 2) * 64;
      c0 = *(const f32x4*)(gp);      c1 = *(const f32x4*)(gp + 4);
      c2 = *(const f32x4*)(gp + 8);  c3 = *(const f32x4*)(gp + 12);
      // wait B(kt) [+ already-old A(kt+1)], keep A(kt+2) in flight
      asm volatile("s_waitcnt vmcnt(4) lgkmcnt(0)\n\ts_barrier" ::: "memory");
    } else {
      // tail: no prefetch issued — must drain fully so all B loads complete
      asm volatile("s_waitcnt vmcnt(0) lgkmcnt(0)\n\ts_barrier" ::: "memory");
    }
    // MFMA phase: ds_read A/B frags + 36 MFMA
    #pragma unroll
    for (int kk = 0; kk < 2; ++kk) {
      short8 af0 = *(const short8*)((const char*)xlds + (wr * 32 + cl) * 144 + kk * 64 + g * 16);
      short8 af1 = *(const short8*)((const char*)xlds + (wr * 32 + 16 + cl) * 144 + kk * 64 + g * 16);
      #pragma unroll
      for (int n = 0; n < 9; ++n) {
        int brr = wc * 144 + n * 16 + cl;
        short8 bf = *(const short8*)(blds + brr * 128 + ((kk * 64 + g * 16) ^ ((brr & 7) << 4)));
        acc[0][n] = __builtin_amdgcn_mfma_f32_16x16x32_bf16(af0, bf, acc[0][n], 0, 0, 0);
        acc[1][n] = __builtin_amdgcn_mfma_f32_16x16x32_bf16(af1, bf, acc[1][n], 0, 0, 0);
      }
    }
  };

  #pragma unroll 1
  for (int kt2 = 0; kt2 < 16; kt2 += 2) {
    step(kt2,     e0, e1, e2, e3);
    step(kt2 + 1, o0, o1, o2, o3);
  }

  // ---- logits: z lives in acc frags n=7 (f=cl) and n=8 (f=16+cl) of wc==1 waves ----
  if (wc == 1) {
    const float w2a = Wa2[cl], w2b = Wa2[16 + cl];
    const float bza = bz[cl], bzb = bz[16 + cl];
    #pragma unroll
    for (int m = 0; m < 2; ++m) {
      float p[4];
      #pragma unroll
      for (int q = 0; q < 4; ++q) {
        float ea = exp2f((acc[m][7][q] + bza) * 2.8853900817779268f);
        float eb = exp2f((acc[m][8][q] + bzb) * 2.8853900817779268f);
        p[q] = (1.f - 2.f / (ea + 1.f)) * w2a + (1.f - 2.f / (eb + 1.f)) * w2b;
      }
      #pragma unroll
      for (int mask = 1; mask <= 8; mask <<= 1)
        #pragma unroll
        for (int q = 0; q < 4; ++q) p[q] += __shfl_xor(p[q], mask);
      if (cl == 0) {
        #pragma unroll
        for (int q = 0; q < 4; ++q)
          logit_s[wr * 32 + m * 16 + g * 4 + q] = p[q];
      }
    }
  }
  __syncthreads();
  if (tid < BM) e_s[tid] = expf(logit_s[tid] + ba2[0]);
  __syncthreads();

  // ---- per-segment weighted accumulation of H columns + sum of e ----
  // NOTE: n-loop compile-time unrolled with wave-uniform predicate — runtime
  // indexing of acc[][] demotes it to scratch (rule #20; round-2 regression).
  const int smin = seg_s[0];
  const int smax = seg_s[BM - 1];
  float ev[8]; int sv[8];
  #pragma unroll
  for (int m = 0; m < 2; ++m)
    #pragma unroll
    for (int q = 0; q < 4; ++q) {
      int rl = wr * 32 + m * 16 + g * 4 + q;
      ev[m * 4 + q] = e_s[rl];
      sv[m * 4 + q] = seg_s[rl];
    }
  for (int s = smin; s <= smax; ++s) {
    float wv[8];
    #pragma unroll
    for (int i = 0; i < 8; ++i) wv[i] = (sv[i] == s) ? ev[i] : 0.f;
    #pragma unroll
    for (int n = 0; n < 9; ++n) {
      if (n < 7 || wc == 0) {          // wave-uniform; indices stay static
        float cs = 0.f;
        #pragma unroll
        for (int m = 0; m < 2; ++m)
          #pragma unroll
          for (int q = 0; q < 4; ++q)
            cs += wv[m * 4 + q] * acc[m][n][q];
        cs += __shfl_xor(cs, 16);
        cs += __shfl_xor(cs, 32);
        if (lane < 16) atomicAdd(&acc_eh[s * DDIM + wc * 144 + n * 16 + cl], cs);
      }
    }
    if (wid == 0) {
      float v = (seg_s[lane] == s) ? e_s[lane] : 0.f;
      #pragma unroll
      for (int mask = 1; mask <= 32; mask <<= 1) v += __shfl_xor(v, mask);
      if (lane == 0) atomicAdd(&accE[s], v);
    }
  }
}

// ---- finalize: M = acc/Sum_e + b1; proj = normalize(M@Wp + bp) ----
__global__ void finalize_k(const float* __restrict__ acc_eh, const float* __restrict__ accE,
                           const float* __restrict__ b1, const float* __restrict__ Wp,
                           const float* __restrict__ bp, float* __restrict__ out) {
  __shared__ float Ml[DDIM];
  const int s = blockIdx.x, t = threadIdx.x;
  const float E = accE[s];
  float m = 0.f;
  if (E > 0.f) m = acc_eh[s * DDIM + t] / E + b1[t];
  out[s * DDIM + t] = m;
  Ml[t] = m;
  __syncthreads();
  if (t < FDIM) {
    float p = bp[t];
    for (int c = 0; c < DDIM; ++c) p += Ml[c] * Wp[c * FDIM + t];
    float n2 = p * p;
    #pragma unroll
    for (int mask = 1; mask <= 16; mask <<= 1) n2 += __shfl_xor(n2, mask);
    out[NSEG * DDIM + s * FDIM + t] = p / fmaxf(sqrtf(n2), 1e-12f);
  }
}

extern "C" void kernel_launch(void* const* d_in, const int* in_sizes, int n_in,
                              void* d_out, int out_size, void* d_ws, size_t ws_size,
                              hipStream_t stream) {
  const float* x   = (const float*)d_in[0];
  const int*   idxs= (const int*)d_in[1];
  const float* W1  = (const float*)d_in[2];
  const float* b1  = (const float*)d_in[3];
  const float* Wa1 = (const float*)d_in[4];
  const float* ba1 = (const float*)d_in[5];
  const float* Wa2 = (const float*)d_in[6];
  const float* ba2 = (const float*)d_in[7];
  const float* Wp  = (const float*)d_in[8];
  const float* bp  = (const float*)d_in[9];
  float* out = (float*)d_out;

  char* ws = (char*)d_ws;
  unsigned short* w1t = (unsigned short*)ws;          // 288*1024 bf16 (alloc 320 rows)
  float* bz     = (float*)(ws + 655360);              // 32 f32
  float* acc_eh = (float*)(ws + 655488);              // 64*256 f32
  float* accE   = (float*)(ws + 721024);              // 64 f32

  const int n = in_sizes[1];                          // 262144 rows
  prep_w1t<<<LDIM, DDIM, 0, stream>>>(W1, Wa1, w1t);
  prep_misc<<<NSEG, DDIM, 0, stream>>>(b1, Wa1, ba1, bz, acc_eh, accE);
  fused_main<<<n / BM, 256, 0, stream>>>(x, idxs, w1t, bz, Wa2, ba2, acc_eh, accE);
  finalize_k<<<NSEG, DDIM, 0, stream>>>(acc_eh, accE, b1, Wp, bp, out);
}

// Round 6
// 568.419 us; speedup vs baseline: 1.3446x; 1.3446x over previous
//
#include <hip/hip_runtime.h>
#include <stdint.h>

#define LDIM 1024
#define DDIM 256
#define FDIM 32
#define NSEG 64
#define BM 64
#define BK 64

typedef __attribute__((ext_vector_type(4))) float f32x4;
typedef __attribute__((ext_vector_type(8))) short short8;
typedef __attribute__((ext_vector_type(4))) unsigned int u32x4;

__device__ __forceinline__ unsigned int pk2bf(float a, float b) {
  union { float f; unsigned int u; } x, y; x.f = a; y.f = b;
  unsigned int ua = x.u + 0x7FFFu + ((x.u >> 16) & 1u);
  unsigned int ub = y.u + 0x7FFFu + ((y.u >> 16) & 1u);
  return (ua >> 16) | (ub & 0xFFFF0000u);
}

__device__ __forceinline__ unsigned short f2bf(float f) {
  union { float f; unsigned int u; } v; v.f = f;
  unsigned int r = v.u + 0x7FFFu + ((v.u >> 16) & 1u);
  return (unsigned short)(r >> 16);
}

// ---- prep: W1^T (bf16) rows 0..255, (W1@Wa1)^T rows 256..287 into ws ----
__global__ void prep_w1t(const float* __restrict__ W1, const float* __restrict__ Wa1,
                         unsigned short* __restrict__ w1t) {
  __shared__ float rowf[DDIM];
  const int k = blockIdx.x;
  const int t = threadIdx.x;
  float v = W1[(size_t)k * DDIM + t];
  rowf[t] = v;
  w1t[(size_t)t * LDIM + k] = f2bf(v);
  __syncthreads();
  if (t < FDIM) {
    float a = 0.f;
    for (int c = 0; c < DDIM; ++c) a += rowf[c] * Wa1[c * FDIM + t];
    w1t[(size_t)(DDIM + t) * LDIM + k] = f2bf(a);
  }
}

// ---- prep: zero accumulators, bz = b1@Wa1 + ba1 ----
__global__ void prep_misc(const float* __restrict__ b1, const float* __restrict__ Wa1,
                          const float* __restrict__ ba1, float* __restrict__ bz,
                          float* __restrict__ acc_eh, float* __restrict__ accE) {
  const int b = blockIdx.x, t = threadIdx.x;
  acc_eh[b * DDIM + t] = 0.f;
  if (t == 0) accE[b] = 0.f;
  if (b == 0 && t < FDIM) {
    float a = ba1[t];
    for (int c = 0; c < DDIM; ++c) a += b1[c] * Wa1[c * FDIM + t];
    bz[t] = a;
  }
}

// K-step as a MACRO: round-5's lambda version was not inlined -> all captured
// state (acc, staging regs) demoted to scratch (VGPR=84, 0.5 GB scratch writes).
// Textual inlining + static names keeps everything in registers (rule #20).
#define STEP(KT, C0, C1, C2, C3)                                                      \
  do {                                                                                \
    __builtin_amdgcn_s_barrier();  /* raw: no vmcnt drain; prefetches stay in flight */\
    _Pragma("unroll")                                                                 \
    for (int j = 0; j < 9; ++j) {                                                     \
      int byteoff = j * 4096 + tid * 16;                                              \
      int brow = byteoff >> 7;                                                        \
      int bcolb = byteoff & 127;                                                      \
      int srcb = brow * 2048 + (KT) * 128 + (bcolb ^ ((brow & 7) << 4));              \
      __builtin_amdgcn_global_load_lds(                                               \
          (const __attribute__((address_space(1))) unsigned int*)(w1tb + srcb),       \
          (__attribute__((address_space(3))) unsigned int*)(blds + j * 4096 + wid * 1024), \
          16, 0, 0);                                                                  \
    }                                                                                 \
    /* pin order: B(kt) loads strictly older than A(kt+2) (vmcnt(4) relies on it) */  \
    __builtin_amdgcn_sched_barrier(0);                                                \
    u32x4 q0, q1;                                                                     \
    q0[0] = pk2bf(C0[0], C0[1]); q0[1] = pk2bf(C0[2], C0[3]);                         \
    q0[2] = pk2bf(C1[0], C1[1]); q0[3] = pk2bf(C1[2], C1[3]);                         \
    q1[0] = pk2bf(C2[0], C2[1]); q1[1] = pk2bf(C2[2], C2[3]);                         \
    q1[2] = pk2bf(C3[0], C3[1]); q1[3] = pk2bf(C3[2], C3[3]);                         \
    *(u32x4*)&xlds[arow][aq * 16] = q0;                                               \
    *(u32x4*)&xlds[arow][aq * 16 + 8] = q1;                                           \
    if ((KT) < 14) {                                                                  \
      const float* gp = gxa + ((KT) + 2) * 64;                                        \
      C0 = *(const f32x4*)(gp);      C1 = *(const f32x4*)(gp + 4);                    \
      C2 = *(const f32x4*)(gp + 8);  C3 = *(const f32x4*)(gp + 12);                   \
      /* drain B(kt) [+A(kt+1)], keep the 4 A(kt+2) loads in flight */                \
      asm volatile("s_waitcnt vmcnt(4) lgkmcnt(0)\n\ts_barrier" ::: "memory");        \
    } else {                                                                          \
      asm volatile("s_waitcnt vmcnt(0) lgkmcnt(0)\n\ts_barrier" ::: "memory");        \
    }                                                                                 \
    _Pragma("unroll")                                                                 \
    for (int kk = 0; kk < 2; ++kk) {                                                  \
      short8 af0 = *(const short8*)((const char*)xlds + (wr * 32 + cl) * 144 + kk * 64 + g * 16);      \
      short8 af1 = *(const short8*)((const char*)xlds + (wr * 32 + 16 + cl) * 144 + kk * 64 + g * 16); \
      _Pragma("unroll")                                                               \
      for (int n = 0; n < 9; ++n) {                                                   \
        int brr = wc * 144 + n * 16 + cl;                                             \
        short8 bf = *(const short8*)(blds + brr * 128 + ((kk * 64 + g * 16) ^ ((brr & 7) << 4)));      \
        acc[0][n] = __builtin_amdgcn_mfma_f32_16x16x32_bf16(af0, bf, acc[0][n], 0, 0, 0);              \
        acc[1][n] = __builtin_amdgcn_mfma_f32_16x16x32_bf16(af1, bf, acc[1][n], 0, 0, 0);              \
      }                                                                               \
    }                                                                                 \
  } while (0)

// ---- main fused kernel: LDS-shared A (x read once) + raw barrier-1 +
//      depth-2 A prefetch + counted-vmcnt barrier-2 ----
__global__ __launch_bounds__(256, 3) void fused_main(
    const float* __restrict__ x, const int* __restrict__ idxs,
    const unsigned short* __restrict__ w1t, const float* __restrict__ bz,
    const float* __restrict__ Wa2, const float* __restrict__ ba2,
    float* __restrict__ acc_eh, float* __restrict__ accE)
{
  __shared__ __align__(16) unsigned short xlds[BM][72];      // 64 rows x 144B (2-way free)
  __shared__ __align__(16) unsigned char blds[288 * 128];    // 288 rows x 128B, XOR-swizzled
  __shared__ float logit_s[BM];
  __shared__ float e_s[BM];
  __shared__ int seg_s[BM];

  const int tid = threadIdx.x;
  const int lane = tid & 63;
  const int wid = tid >> 6;       // 0..3
  const int wr = wid >> 1;        // 0..1 : 32-row half
  const int wc = wid & 1;         // 0..1 : 144-col half
  const int g = lane >> 4;
  const int cl = lane & 15;
  const int row0 = blockIdx.x * BM;

  if (tid < BM) seg_s[tid] = idxs[row0 + tid];

  f32x4 acc[2][9];
  const f32x4 zero4 = {0.f, 0.f, 0.f, 0.f};
  #pragma unroll
  for (int m = 0; m < 2; ++m)
    #pragma unroll
    for (int n = 0; n < 9; ++n) acc[m][n] = zero4;

  const int arow = tid >> 2;
  const int aq = tid & 3;
  const char* w1tb = (const char*)w1t;
  const float* gxa = x + (size_t)(row0 + arow) * LDIM + aq * 16;

  // two named staging sets (depth-2 A pipeline; static names — rule #20)
  f32x4 e0, e1, e2, e3;   // even-kt set
  f32x4 o0, o1, o2, o3;   // odd-kt set
  e0 = *(const f32x4*)(gxa);      e1 = *(const f32x4*)(gxa + 4);
  e2 = *(const f32x4*)(gxa + 8);  e3 = *(const f32x4*)(gxa + 12);
  o0 = *(const f32x4*)(gxa + 64); o1 = *(const f32x4*)(gxa + 68);
  o2 = *(const f32x4*)(gxa + 72); o3 = *(const f32x4*)(gxa + 76);

  #pragma unroll 1
  for (int kt2 = 0; kt2 < 16; kt2 += 2) {
    STEP(kt2,     e0, e1, e2, e3);
    STEP(kt2 + 1, o0, o1, o2, o3);
  }

  // ---- logits: z lives in acc frags n=7 (f=cl) and n=8 (f=16+cl) of wc==1 waves ----
  if (wc == 1) {
    const float w2a = Wa2[cl], w2b = Wa2[16 + cl];
    const float bza = bz[cl], bzb = bz[16 + cl];
    #pragma unroll
    for (int m = 0; m < 2; ++m) {
      float p[4];
      #pragma unroll
      for (int q = 0; q < 4; ++q) {
        float ea = exp2f((acc[m][7][q] + bza) * 2.8853900817779268f);
        float eb = exp2f((acc[m][8][q] + bzb) * 2.8853900817779268f);
        p[q] = (1.f - 2.f / (ea + 1.f)) * w2a + (1.f - 2.f / (eb + 1.f)) * w2b;
      }
      #pragma unroll
      for (int mask = 1; mask <= 8; mask <<= 1)
        #pragma unroll
        for (int q = 0; q < 4; ++q) p[q] += __shfl_xor(p[q], mask);
      if (cl == 0) {
        #pragma unroll
        for (int q = 0; q < 4; ++q)
          logit_s[wr * 32 + m * 16 + g * 4 + q] = p[q];
      }
    }
  }
  __syncthreads();
  if (tid < BM) e_s[tid] = expf(logit_s[tid] + ba2[0]);
  __syncthreads();

  // ---- per-segment weighted accumulation of H columns + sum of e ----
  // NOTE: n-loop compile-time unrolled with wave-uniform predicate — runtime
  // indexing of acc[][] demotes it to scratch (rule #20; round-2 regression).
  const int smin = seg_s[0];
  const int smax = seg_s[BM - 1];
  float ev[8]; int sv[8];
  #pragma unroll
  for (int m = 0; m < 2; ++m)
    #pragma unroll
    for (int q = 0; q < 4; ++q) {
      int rl = wr * 32 + m * 16 + g * 4 + q;
      ev[m * 4 + q] = e_s[rl];
      sv[m * 4 + q] = seg_s[rl];
    }
  for (int s = smin; s <= smax; ++s) {
    float wv[8];
    #pragma unroll
    for (int i = 0; i < 8; ++i) wv[i] = (sv[i] == s) ? ev[i] : 0.f;
    #pragma unroll
    for (int n = 0; n < 9; ++n) {
      if (n < 7 || wc == 0) {          // wave-uniform; indices stay static
        float cs = 0.f;
        #pragma unroll
        for (int m = 0; m < 2; ++m)
          #pragma unroll
          for (int q = 0; q < 4; ++q)
            cs += wv[m * 4 + q] * acc[m][n][q];
        cs += __shfl_xor(cs, 16);
        cs += __shfl_xor(cs, 32);
        if (lane < 16) atomicAdd(&acc_eh[s * DDIM + wc * 144 + n * 16 + cl], cs);
      }
    }
    if (wid == 0) {
      float v = (seg_s[lane] == s) ? e_s[lane] : 0.f;
      #pragma unroll
      for (int mask = 1; mask <= 32; mask <<= 1) v += __shfl_xor(v, mask);
      if (lane == 0) atomicAdd(&accE[s], v);
    }
  }
}

// ---- finalize: M = acc/Sum_e + b1; proj = normalize(M@Wp + bp) ----
__global__ void finalize_k(const float* __restrict__ acc_eh, const float* __restrict__ accE,
                           const float* __restrict__ b1, const float* __restrict__ Wp,
                           const float* __restrict__ bp, float* __restrict__ out) {
  __shared__ float Ml[DDIM];
  const int s = blockIdx.x, t = threadIdx.x;
  const float E = accE[s];
  float m = 0.f;
  if (E > 0.f) m = acc_eh[s * DDIM + t] / E + b1[t];
  out[s * DDIM + t] = m;
  Ml[t] = m;
  __syncthreads();
  if (t < FDIM) {
    float p = bp[t];
    for (int c = 0; c < DDIM; ++c) p += Ml[c] * Wp[c * FDIM + t];
    float n2 = p * p;
    #pragma unroll
    for (int mask = 1; mask <= 16; mask <<= 1) n2 += __shfl_xor(n2, mask);
    out[NSEG * DDIM + s * FDIM + t] = p / fmaxf(sqrtf(n2), 1e-12f);
  }
}

extern "C" void kernel_launch(void* const* d_in, const int* in_sizes, int n_in,
                              void* d_out, int out_size, void* d_ws, size_t ws_size,
                              hipStream_t stream) {
  const float* x   = (const float*)d_in[0];
  const int*   idxs= (const int*)d_in[1];
  const float* W1  = (const float*)d_in[2];
  const float* b1  = (const float*)d_in[3];
  const float* Wa1 = (const float*)d_in[4];
  const float* ba1 = (const float*)d_in[5];
  const float* Wa2 = (const float*)d_in[6];
  const float* ba2 = (const float*)d_in[7];
  const float* Wp  = (const float*)d_in[8];
  const float* bp  = (const float*)d_in[9];
  float* out = (float*)d_out;

  char* ws = (char*)d_ws;
  unsigned short* w1t = (unsigned short*)ws;          // 288*1024 bf16 (alloc 320 rows)
  float* bz     = (float*)(ws + 655360);              // 32 f32
  float* acc_eh = (float*)(ws + 655488);              // 64*256 f32
  float* accE   = (float*)(ws + 721024);              // 64 f32

  const int n = in_sizes[1];                          // 262144 rows
  prep_w1t<<<LDIM, DDIM, 0, stream>>>(W1, Wa1, w1t);
  prep_misc<<<NSEG, DDIM, 0, stream>>>(b1, Wa1, ba1, bz, acc_eh, accE);
  fused_main<<<n / BM, 256, 0, stream>>>(x, idxs, w1t, bz, Wa2, ba2, acc_eh, accE);
  finalize_k<<<NSEG, DDIM, 0, stream>>>(acc_eh, accE, b1, Wp, bp, out);
}

// Round 7
// 358.097 us; speedup vs baseline: 2.1343x; 1.5873x over previous
//
#include <hip/hip_runtime.h>
#include <stdint.h>

#define LDIM 1024
#define DDIM 256
#define FDIM 32
#define NSEG 64
#define BM 64
#define BK 64

typedef __attribute__((ext_vector_type(4))) float f32x4;
typedef __attribute__((ext_vector_type(8))) short short8;
typedef __attribute__((ext_vector_type(4))) unsigned int u32x4;

__device__ __forceinline__ unsigned int pk2bf(float a, float b) {
  union { float f; unsigned int u; } x, y; x.f = a; y.f = b;
  unsigned int ua = x.u + 0x7FFFu + ((x.u >> 16) & 1u);
  unsigned int ub = y.u + 0x7FFFu + ((y.u >> 16) & 1u);
  return (ua >> 16) | (ub & 0xFFFF0000u);
}

__device__ __forceinline__ unsigned short f2bf(float f) {
  union { float f; unsigned int u; } v; v.f = f;
  unsigned int r = v.u + 0x7FFFu + ((v.u >> 16) & 1u);
  return (unsigned short)(r >> 16);
}

__device__ __forceinline__ short8 pack8(f32x4 a, f32x4 b) {
  union { u32x4 u; short8 s; } r;
  r.u[0] = pk2bf(a[0], a[1]); r.u[1] = pk2bf(a[2], a[3]);
  r.u[2] = pk2bf(b[0], b[1]); r.u[3] = pk2bf(b[2], b[3]);
  return r.s;
}

// ---- prep: W1^T (bf16) rows 0..255, (W1@Wa1)^T rows 256..287 into ws ----
__global__ void prep_w1t(const float* __restrict__ W1, const float* __restrict__ Wa1,
                         unsigned short* __restrict__ w1t) {
  __shared__ float rowf[DDIM];
  const int k = blockIdx.x;
  const int t = threadIdx.x;
  float v = W1[(size_t)k * DDIM + t];
  rowf[t] = v;
  w1t[(size_t)t * LDIM + k] = f2bf(v);
  __syncthreads();
  if (t < FDIM) {
    float a = 0.f;
    for (int c = 0; c < DDIM; ++c) a += rowf[c] * Wa1[c * FDIM + t];
    w1t[(size_t)(DDIM + t) * LDIM + k] = f2bf(a);
  }
}

// ---- prep: zero accumulators, bz = b1@Wa1 + ba1 ----
__global__ void prep_misc(const float* __restrict__ b1, const float* __restrict__ Wa1,
                          const float* __restrict__ ba1, float* __restrict__ bz,
                          float* __restrict__ acc_eh, float* __restrict__ accE) {
  const int b = blockIdx.x, t = threadIdx.x;
  acc_eh[b * DDIM + t] = 0.f;
  if (t == 0) accE[b] = 0.f;
  if (b == 0 && t < FDIM) {
    float a = ba1[t];
    for (int c = 0; c < DDIM; ++c) a += b1[c] * Wa1[c * FDIM + t];
    bz[t] = a;
  }
}

// ---- main fused kernel: row-split waves (A reg-direct, x read once),
//      B staged via global_load_lds, round-3 proven 2x__syncthreads loop ----
__global__ __launch_bounds__(256, 4) void fused_main(
    const float* __restrict__ x, const int* __restrict__ idxs,
    const unsigned short* __restrict__ w1t, const float* __restrict__ bz,
    const float* __restrict__ Wa2, const float* __restrict__ ba2,
    float* __restrict__ acc_eh, float* __restrict__ accE)
{
  __shared__ __align__(16) unsigned char blds[288 * 128];    // 288 rows x 128B, XOR-swizzled
  __shared__ float logit_s[BM];
  __shared__ float e_s[BM];
  __shared__ int seg_s[BM];

  const int tid = threadIdx.x;
  const int lane = tid & 63;
  const int wid = tid >> 6;       // 0..3 : 16-row slice owner
  const int g = lane >> 4;        // 0..3 : k-subchunk
  const int cl = lane & 15;       // A-row within slice / B-col within frag
  const int row0 = blockIdx.x * BM;

  if (tid < BM) seg_s[tid] = idxs[row0 + tid];

  // acc[n]: C rows = wid*16 + g*4 + q, cols = n*16 + cl (n=16,17 are z-cols)
  f32x4 acc[18];
  const f32x4 zero4 = {0.f, 0.f, 0.f, 0.f};
  #pragma unroll
  for (int n = 0; n < 18; ++n) acc[n] = zero4;

  const char* w1tb = (const char*)w1t;
  // lane's A row: row0 + wid*16 + cl; k base = g*8 (8 consecutive f32 per kk)
  const float* gxa = x + (size_t)(row0 + wid * 16 + cl) * LDIM + g * 8;

  f32x4 s0, s1, s2, s3;           // A staging (f32): kk=0 -> s0,s1 ; kk=1 -> s2,s3
  s0 = *(const f32x4*)(gxa);      s1 = *(const f32x4*)(gxa + 4);
  s2 = *(const f32x4*)(gxa + 32); s3 = *(const f32x4*)(gxa + 36);

  #pragma unroll 1
  for (int kt = 0; kt < 16; ++kt) {
    __syncthreads();   // blds consumed by all waves (prev step); drains pipe
    // stage B(kt): 9 x global_load_lds (source pre-inverse-swizzled)
    #pragma unroll
    for (int j = 0; j < 9; ++j) {
      int byteoff = j * 4096 + tid * 16;
      int brow = byteoff >> 7;
      int bcolb = byteoff & 127;
      int srcb = brow * 2048 + kt * 128 + (bcolb ^ ((brow & 7) << 4));
      __builtin_amdgcn_global_load_lds(
          (const __attribute__((address_space(1))) unsigned int*)(w1tb + srcb),
          (__attribute__((address_space(3))) unsigned int*)(blds + j * 4096 + wid * 1024),
          16, 0, 0);
    }
    // convert A(kt) to bf16 frags in-register (covers part of B latency)
    short8 af0 = pack8(s0, s1);
    short8 af1 = pack8(s2, s3);
    __syncthreads();   // B(kt) arrived
    // prefetch A(kt+1): in flight across the MFMA phase
    if (kt < 15) {
      const float* gp = gxa + (kt + 1) * 64;
      s0 = *(const f32x4*)(gp);      s1 = *(const f32x4*)(gp + 4);
      s2 = *(const f32x4*)(gp + 32); s3 = *(const f32x4*)(gp + 36);
    }
    // MFMA phase: 36 ds_read_b128 + 36 MFMA (single base reg; n*128 folds to offset)
    #pragma unroll
    for (int kk = 0; kk < 2; ++kk) {
      #pragma unroll
      for (int n = 0; n < 18; ++n) {
        int brr = n * 16 + cl;
        short8 bf = *(const short8*)(blds + brr * 128 + ((kk * 64 + g * 16) ^ ((cl & 7) << 4)));
        acc[n] = __builtin_amdgcn_mfma_f32_16x16x32_bf16(kk ? af1 : af0, bf, acc[n], 0, 0, 0);
      }
    }
  }

  // ---- logits: z in acc[16] (f=cl) and acc[17] (f=16+cl); wave-local rows ----
  {
    const float w2a = Wa2[cl], w2b = Wa2[16 + cl];
    const float bza = bz[cl], bzb = bz[16 + cl];
    float p[4];
    #pragma unroll
    for (int q = 0; q < 4; ++q) {
      float ea = exp2f((acc[16][q] + bza) * 2.8853900817779268f);
      float eb = exp2f((acc[17][q] + bzb) * 2.8853900817779268f);
      p[q] = (1.f - 2.f / (ea + 1.f)) * w2a + (1.f - 2.f / (eb + 1.f)) * w2b;
    }
    #pragma unroll
    for (int mask = 1; mask <= 8; mask <<= 1)
      #pragma unroll
      for (int q = 0; q < 4; ++q) p[q] += __shfl_xor(p[q], mask);
    if (cl == 0) {
      #pragma unroll
      for (int q = 0; q < 4; ++q)
        logit_s[wid * 16 + g * 4 + q] = p[q];
    }
  }
  __syncthreads();
  if (tid < BM) e_s[tid] = expf(logit_s[tid] + ba2[0]);
  __syncthreads();

  // ---- per-segment weighted accumulation of H columns + sum of e ----
  // n-loop fully unrolled, static indices (rule #20 — rounds 2/5 regressions).
  const int smin = seg_s[0];
  const int smax = seg_s[BM - 1];
  float ev[4]; int sv[4];
  #pragma unroll
  for (int q = 0; q < 4; ++q) {
    int rl = wid * 16 + g * 4 + q;
    ev[q] = e_s[rl];
    sv[q] = seg_s[rl];
  }
  for (int s = smin; s <= smax; ++s) {
    float wv[4];
    #pragma unroll
    for (int q = 0; q < 4; ++q) wv[q] = (sv[q] == s) ? ev[q] : 0.f;
    #pragma unroll
    for (int n = 0; n < 16; ++n) {       // H cols only (16,17 are z)
      float cs = 0.f;
      #pragma unroll
      for (int q = 0; q < 4; ++q) cs += wv[q] * acc[n][q];
      cs += __shfl_xor(cs, 16);
      cs += __shfl_xor(cs, 32);          // summed over g -> wave's 16 rows
      if (lane < 16) atomicAdd(&acc_eh[s * DDIM + n * 16 + cl], cs);
    }
    if (wid == 0) {
      float v = (seg_s[lane] == s) ? e_s[lane] : 0.f;
      #pragma unroll
      for (int mask = 1; mask <= 32; mask <<= 1) v += __shfl_xor(v, mask);
      if (lane == 0) atomicAdd(&accE[s], v);
    }
  }
}

// ---- finalize: M = acc/Sum_e + b1; proj = normalize(M@Wp + bp) ----
__global__ void finalize_k(const float* __restrict__ acc_eh, const float* __restrict__ accE,
                           const float* __restrict__ b1, const float* __restrict__ Wp,
                           const float* __restrict__ bp, float* __restrict__ out) {
  __shared__ float Ml[DDIM];
  const int s = blockIdx.x, t = threadIdx.x;
  const float E = accE[s];
  float m = 0.f;
  if (E > 0.f) m = acc_eh[s * DDIM + t] / E + b1[t];
  out[s * DDIM + t] = m;
  Ml[t] = m;
  __syncthreads();
  if (t < FDIM) {
    float p = bp[t];
    for (int c = 0; c < DDIM; ++c) p += Ml[c] * Wp[c * FDIM + t];
    float n2 = p * p;
    #pragma unroll
    for (int mask = 1; mask <= 16; mask <<= 1) n2 += __shfl_xor(n2, mask);
    out[NSEG * DDIM + s * FDIM + t] = p / fmaxf(sqrtf(n2), 1e-12f);
  }
}

extern "C" void kernel_launch(void* const* d_in, const int* in_sizes, int n_in,
                              void* d_out, int out_size, void* d_ws, size_t ws_size,
                              hipStream_t stream) {
  const float* x   = (const float*)d_in[0];
  const int*   idxs= (const int*)d_in[1];
  const float* W1  = (const float*)d_in[2];
  const float* b1  = (const float*)d_in[3];
  const float* Wa1 = (const float*)d_in[4];
  const float* ba1 = (const float*)d_in[5];
  const float* Wa2 = (const float*)d_in[6];
  const float* ba2 = (const float*)d_in[7];
  const float* Wp  = (const float*)d_in[8];
  const float* bp  = (const float*)d_in[9];
  float* out = (float*)d_out;

  char* ws = (char*)d_ws;
  unsigned short* w1t = (unsigned short*)ws;          // 288*1024 bf16 (alloc 320 rows)
  float* bz     = (float*)(ws + 655360);              // 32 f32
  float* acc_eh = (float*)(ws + 655488);              // 64*256 f32
  float* accE   = (float*)(ws + 721024);              // 64 f32

  const int n = in_sizes[1];                          // 262144 rows
  prep_w1t<<<LDIM, DDIM, 0, stream>>>(W1, Wa1, w1t);
  prep_misc<<<NSEG, DDIM, 0, stream>>>(b1, Wa1, ba1, bz, acc_eh, accE);
  fused_main<<<n / BM, 256, 0, stream>>>(x, idxs, w1t, bz, Wa2, ba2, acc_eh, accE);
  finalize_k<<<NSEG, DDIM, 0, stream>>>(acc_eh, accE, b1, Wp, bp, out);
}

// Round 8
// 307.989 us; speedup vs baseline: 2.4816x; 1.1627x over previous
//
#include <hip/hip_runtime.h>
#include <stdint.h>

#define LDIM 1024
#define DDIM 256
#define FDIM 32
#define NSEG 64
#define BM 64
#define BK 64

typedef __attribute__((ext_vector_type(4))) float f32x4;
typedef __attribute__((ext_vector_type(8))) short short8;
typedef __attribute__((ext_vector_type(4))) unsigned int u32x4;

__device__ __forceinline__ unsigned int pk2bf(float a, float b) {
  union { float f; unsigned int u; } x, y; x.f = a; y.f = b;
  unsigned int ua = x.u + 0x7FFFu + ((x.u >> 16) & 1u);
  unsigned int ub = y.u + 0x7FFFu + ((y.u >> 16) & 1u);
  return (ua >> 16) | (ub & 0xFFFF0000u);
}

__device__ __forceinline__ unsigned short f2bf(float f) {
  union { float f; unsigned int u; } v; v.f = f;
  unsigned int r = v.u + 0x7FFFu + ((v.u >> 16) & 1u);
  return (unsigned short)(r >> 16);
}

__device__ __forceinline__ short8 pack8(f32x4 a, f32x4 b) {
  union { u32x4 u; short8 s; } r;
  r.u[0] = pk2bf(a[0], a[1]); r.u[1] = pk2bf(a[2], a[3]);
  r.u[2] = pk2bf(b[0], b[1]); r.u[3] = pk2bf(b[2], b[3]);
  return r.s;
}

// ---- prep: W1^T (bf16) rows 0..255, (W1@Wa1)^T rows 256..287 into ws ----
__global__ void prep_w1t(const float* __restrict__ W1, const float* __restrict__ Wa1,
                         unsigned short* __restrict__ w1t) {
  __shared__ float rowf[DDIM];
  const int k = blockIdx.x;
  const int t = threadIdx.x;
  float v = W1[(size_t)k * DDIM + t];
  rowf[t] = v;
  w1t[(size_t)t * LDIM + k] = f2bf(v);
  __syncthreads();
  if (t < FDIM) {
    float a = 0.f;
    for (int c = 0; c < DDIM; ++c) a += rowf[c] * Wa1[c * FDIM + t];
    w1t[(size_t)(DDIM + t) * LDIM + k] = f2bf(a);
  }
}

// ---- prep: zero accumulators, bz = b1@Wa1 + ba1 ----
__global__ void prep_misc(const float* __restrict__ b1, const float* __restrict__ Wa1,
                          const float* __restrict__ ba1, float* __restrict__ bz,
                          float* __restrict__ acc_eh, float* __restrict__ accE) {
  const int b = blockIdx.x, t = threadIdx.x;
  acc_eh[b * DDIM + t] = 0.f;
  if (t == 0) accE[b] = 0.f;
  if (b == 0 && t < FDIM) {
    float a = ba1[t];
    for (int c = 0; c < DDIM; ++c) a += b1[c] * Wa1[c * FDIM + t];
    bz[t] = a;
  }
}

// ---- main fused kernel: row-split waves (A reg-direct, x read exactly once).
// r7 regression root-cause fix: __launch_bounds__(256,3) — the (256,4) build
// capped VGPR at 128 < the ~135 this kernel needs -> spill-to-scratch per step.
// r4 proved this per-lane A access pattern sustains ~90% of achievable HBM. ----
__global__ __launch_bounds__(256, 3) void fused_main(
    const float* __restrict__ x, const int* __restrict__ idxs,
    const unsigned short* __restrict__ w1t, const float* __restrict__ bz,
    const float* __restrict__ Wa2, const float* __restrict__ ba2,
    float* __restrict__ acc_eh, float* __restrict__ accE)
{
  __shared__ __align__(16) unsigned char blds[288 * 128];    // 288 rows x 128B, XOR-swizzled
  __shared__ float logit_s[BM];
  __shared__ float e_s[BM];
  __shared__ int seg_s[BM];

  const int tid = threadIdx.x;
  const int lane = tid & 63;
  const int wid = tid >> 6;       // 0..3 : 16-row slice owner
  const int g = lane >> 4;        // 0..3 : k-subchunk
  const int cl = lane & 15;       // A-row within slice / B-col within frag
  const int row0 = blockIdx.x * BM;

  if (tid < BM) seg_s[tid] = idxs[row0 + tid];

  // acc[n]: C rows = wid*16 + g*4 + q, cols = n*16 + cl (n=16,17 are z-cols)
  f32x4 acc[18];
  const f32x4 zero4 = {0.f, 0.f, 0.f, 0.f};
  #pragma unroll
  for (int n = 0; n < 18; ++n) acc[n] = zero4;

  const char* w1tb = (const char*)w1t;
  // lane's A row: row0 + wid*16 + cl; k base = g*8 (8 consecutive f32 per kk)
  const float* gxa = x + (size_t)(row0 + wid * 16 + cl) * LDIM + g * 8;

  f32x4 s0, s1, s2, s3;           // A staging (f32): kk=0 -> s0,s1 ; kk=1 -> s2,s3
  s0 = *(const f32x4*)(gxa);      s1 = *(const f32x4*)(gxa + 4);
  s2 = *(const f32x4*)(gxa + 32); s3 = *(const f32x4*)(gxa + 36);

  #pragma unroll 1
  for (int kt = 0; kt < 16; ++kt) {
    // barrier-1: RAW — each wave's blds ds_reads were consumed by its MFMAs
    // (compiler lgkmcnt) and prior gload_lds drained at barrier-2; only the
    // A(kt) register prefetch is outstanding, and it may stay in flight.
    __builtin_amdgcn_s_barrier();
    // stage B(kt): 9 x global_load_lds (source pre-inverse-swizzled)
    #pragma unroll
    for (int j = 0; j < 9; ++j) {
      int byteoff = j * 4096 + tid * 16;
      int brow = byteoff >> 7;
      int bcolb = byteoff & 127;
      int srcb = brow * 2048 + kt * 128 + (bcolb ^ ((brow & 7) << 4));
      __builtin_amdgcn_global_load_lds(
          (const __attribute__((address_space(1))) unsigned int*)(w1tb + srcb),
          (__attribute__((address_space(3))) unsigned int*)(blds + j * 4096 + wid * 1024),
          16, 0, 0);
    }
    // convert A(kt) to bf16 frags in-register (compiler waits just the A loads;
    // also covers part of B latency)
    short8 af0 = pack8(s0, s1);
    short8 af1 = pack8(s2, s3);
    __syncthreads();   // B(kt) arrived (vmcnt0 drain — B was issued ~150cyc ago)
    // prefetch A(kt+1): in flight across the MFMA phase + next barrier-1
    if (kt < 15) {
      const float* gp = gxa + (kt + 1) * 64;
      s0 = *(const f32x4*)(gp);      s1 = *(const f32x4*)(gp + 4);
      s2 = *(const f32x4*)(gp + 32); s3 = *(const f32x4*)(gp + 36);
    }
    // MFMA phase: 36 ds_read_b128 + 36 MFMA (single base; offsets fold to imm)
    #pragma unroll
    for (int kk = 0; kk < 2; ++kk) {
      #pragma unroll
      for (int n = 0; n < 18; ++n) {
        int brr = n * 16 + cl;
        short8 bf = *(const short8*)(blds + brr * 128 + ((kk * 64 + g * 16) ^ ((cl & 7) << 4)));
        acc[n] = __builtin_amdgcn_mfma_f32_16x16x32_bf16(kk ? af1 : af0, bf, acc[n], 0, 0, 0);
      }
    }
  }

  // ---- logits: z in acc[16] (f=cl) and acc[17] (f=16+cl); wave-local rows ----
  {
    const float w2a = Wa2[cl], w2b = Wa2[16 + cl];
    const float bza = bz[cl], bzb = bz[16 + cl];
    float p[4];
    #pragma unroll
    for (int q = 0; q < 4; ++q) {
      float ea = exp2f((acc[16][q] + bza) * 2.8853900817779268f);
      float eb = exp2f((acc[17][q] + bzb) * 2.8853900817779268f);
      p[q] = (1.f - 2.f / (ea + 1.f)) * w2a + (1.f - 2.f / (eb + 1.f)) * w2b;
    }
    #pragma unroll
    for (int mask = 1; mask <= 8; mask <<= 1)
      #pragma unroll
      for (int q = 0; q < 4; ++q) p[q] += __shfl_xor(p[q], mask);
    if (cl == 0) {
      #pragma unroll
      for (int q = 0; q < 4; ++q)
        logit_s[wid * 16 + g * 4 + q] = p[q];
    }
  }
  __syncthreads();
  if (tid < BM) e_s[tid] = expf(logit_s[tid] + ba2[0]);
  __syncthreads();

  // ---- per-segment weighted accumulation of H columns + sum of e ----
  // n-loop fully unrolled, static indices (rule #20 — rounds 2/5 regressions).
  const int smin = seg_s[0];
  const int smax = seg_s[BM - 1];
  float ev[4]; int sv[4];
  #pragma unroll
  for (int q = 0; q < 4; ++q) {
    int rl = wid * 16 + g * 4 + q;
    ev[q] = e_s[rl];
    sv[q] = seg_s[rl];
  }
  for (int s = smin; s <= smax; ++s) {
    float wv[4];
    #pragma unroll
    for (int q = 0; q < 4; ++q) wv[q] = (sv[q] == s) ? ev[q] : 0.f;
    #pragma unroll
    for (int n = 0; n < 16; ++n) {       // H cols only (16,17 are z)
      float cs = 0.f;
      #pragma unroll
      for (int q = 0; q < 4; ++q) cs += wv[q] * acc[n][q];
      cs += __shfl_xor(cs, 16);
      cs += __shfl_xor(cs, 32);          // summed over g -> wave's 16 rows
      if (lane < 16) atomicAdd(&acc_eh[s * DDIM + n * 16 + cl], cs);
    }
    if (wid == 0) {
      float v = (seg_s[lane] == s) ? e_s[lane] : 0.f;
      #pragma unroll
      for (int mask = 1; mask <= 32; mask <<= 1) v += __shfl_xor(v, mask);
      if (lane == 0) atomicAdd(&accE[s], v);
    }
  }
}

// ---- finalize: M = acc/Sum_e + b1; proj = normalize(M@Wp + bp) ----
__global__ void finalize_k(const float* __restrict__ acc_eh, const float* __restrict__ accE,
                           const float* __restrict__ b1, const float* __restrict__ Wp,
                           const float* __restrict__ bp, float* __restrict__ out) {
  __shared__ float Ml[DDIM];
  const int s = blockIdx.x, t = threadIdx.x;
  const float E = accE[s];
  float m = 0.f;
  if (E > 0.f) m = acc_eh[s * DDIM + t] / E + b1[t];
  out[s * DDIM + t] = m;
  Ml[t] = m;
  __syncthreads();
  if (t < FDIM) {
    float p = bp[t];
    for (int c = 0; c < DDIM; ++c) p += Ml[c] * Wp[c * FDIM + t];
    float n2 = p * p;
    #pragma unroll
    for (int mask = 1; mask <= 16; mask <<= 1) n2 += __shfl_xor(n2, mask);
    out[NSEG * DDIM + s * FDIM + t] = p / fmaxf(sqrtf(n2), 1e-12f);
  }
}

extern "C" void kernel_launch(void* const* d_in, const int* in_sizes, int n_in,
                              void* d_out, int out_size, void* d_ws, size_t ws_size,
                              hipStream_t stream) {
  const float* x   = (const float*)d_in[0];
  const int*   idxs= (const int*)d_in[1];
  const float* W1  = (const float*)d_in[2];
  const float* b1  = (const float*)d_in[3];
  const float* Wa1 = (const float*)d_in[4];
  const float* ba1 = (const float*)d_in[5];
  const float* Wa2 = (const float*)d_in[6];
  const float* ba2 = (const float*)d_in[7];
  const float* Wp  = (const float*)d_in[8];
  const float* bp  = (const float*)d_in[9];
  float* out = (float*)d_out;

  char* ws = (char*)d_ws;
  unsigned short* w1t = (unsigned short*)ws;          // 288*1024 bf16 (alloc 320 rows)
  float* bz     = (float*)(ws + 655360);              // 32 f32
  float* acc_eh = (float*)(ws + 655488);              // 64*256 f32
  float* accE   = (float*)(ws + 721024);              // 64 f32

  const int n = in_sizes[1];                          // 262144 rows
  prep_w1t<<<LDIM, DDIM, 0, stream>>>(W1, Wa1, w1t);
  prep_misc<<<NSEG, DDIM, 0, stream>>>(b1, Wa1, ba1, bz, acc_eh, accE);
  fused_main<<<n / BM, 256, 0, stream>>>(x, idxs, w1t, bz, Wa2, ba2, acc_eh, accE);
  finalize_k<<<NSEG, DDIM, 0, stream>>>(acc_eh, accE, b1, Wp, bp, out);
}